// Round 4
// baseline (111.841 us; speedup 1.0000x reference)
//
#include <hip/hip_runtime.h>
#include <math.h>

#define C_NUM 80
#define T_NUM 256
#define EPSF  1e-7f
#define NBLK  2112              // 1600 (s0) + 400 (s1) + 112 (s2, 7/image)

__device__ __forceinline__ float softplusf(float z) {
    return fmaxf(z, 0.0f) + log1pf(expf(-fabsf(z)));
}

// Read-once 43MB class stream: nontemporal (streaming) loads — data is never
// re-read by anyone, so skip L2 allocation/eviction churn.
// __builtin_nontemporal_load needs a NATIVE vector type (not HIP_vector_type),
// so go through a clang ext_vector and bit-cast.
typedef float vfloat4 __attribute__((ext_vector_type(4)));
__device__ __forceinline__ float4 ldnt4(const float* p) {
    vfloat4 v = __builtin_nontemporal_load(reinterpret_cast<const vfloat4*>(p));
    return make_float4(v.x, v.y, v.z, v.w);
}
__device__ __forceinline__ float ldnt(const float* p) {
    return __builtin_nontemporal_load(p);
}

// One block = 64 anchor slots of ONE (scale, image). 2112 blocks.
// Wave w owns classes [20w,20w+20); lane=(cq,ag): cq=lane>>4 -> 5-class strip,
// ag=lane&15 -> float4 anchor group a0+4ag. Wave 0 additionally runs the
// match phase (1 anchor/lane) overlapped with the in-flight class stream.
//
// R10 = R9 with the nontemporal builtin fixed to use ext_vector_type.
// R9 changes vs R8 (which was NULL vs the 106.8us baseline -> DS/issue work
// is already hidden; attack the stream + barrier count instead):
//  - class + reg loads are NONTEMPORAL (read-once stream, no L2 alloc).
//  - compaction writes s_list at fixed per-wave segments (wave*64+pfx) and
//    the match loop walks the 4 segments in wave order (same ascending-tid
//    order -> same first-max tie). This deletes the cross-wave prefix-base
//    and merges the first two __syncthreads: 4 barriers -> 3.
//
// NO fences / NO completion counter: per-block partials are plain stores;
// a second kernel (launch boundary = the sync) folds them. R5-R7 showed
// __threadfence's per-block L2 writeback serializes at ~35-70ns/block.
// Single-kernel last-block folding is blocked by workspace re-poisoning
// (atomic counter would start at garbage), and coop-launch can't co-reside
// 2112x4 waves.
__global__ __launch_bounds__(256)
void yolo_main(const float* __restrict__ cls0, const float* __restrict__ cls1,
               const float* __restrict__ cls2,
               const float* __restrict__ reg0, const float* __restrict__ reg1,
               const float* __restrict__ reg2,
               const float* __restrict__ tboxes, const int* __restrict__ t_batch,
               const int* __restrict__ t_cls, float4* __restrict__ pblk)
{
    __shared__ float s_x1[T_NUM], s_y1[T_NUM], s_x2[T_NUM], s_y2[T_NUM], s_ar[T_NUM];
    __shared__ int   s_tc[T_NUM];
    __shared__ int   s_list[T_NUM];   // 4 segments of 64: wave w owns [64w, 64w+cnt_w)
    __shared__ int   s_wcnt[4];
    __shared__ float4 s_wmax4[256];   // flat[tid] == [wave][cq][ag]: 5-class max of 4 anchors
    __shared__ int   s_btc[64] __attribute__((aligned(16)));
    __shared__ float s_red[4][4];

    const int tid = threadIdx.x;
    const int bid = blockIdx.x;
    const int lane = tid & 63, wave = tid >> 6;
    const int cq = lane >> 4, ag = lane & 15;

    int b, a0, A, H; float stride;
    const float *clsp, *regp;
    if (bid < 1600)      { b = bid / 100;            a0 = (bid % 100) * 64; A = 6400; H = 80; stride =  8.f; clsp = cls0; regp = reg0; }
    else if (bid < 2000) { int r = bid - 1600; b = r / 25; a0 = (r % 25) * 64; A = 1600; H = 40; stride = 16.f; clsp = cls1; regp = reg1; }
    else                 { int r = bid - 2000; b = r / 7;  a0 = (r % 7)  * 64; A = 400;  H = 20; stride = 32.f; clsp = cls2; regp = reg2; }

    // ---- issue the 43MB class stream FIRST (5 independent float4/thread) ----
    const int cbase = wave * 20 + cq * 5;
    const int ga = a0 + 4 * ag;
    const float* p = clsp + ((size_t)(b * C_NUM + cbase)) * (size_t)A + ((ga < A) ? ga : a0);
    float4 z0 = ldnt4(p);
    float4 z1 = ldnt4(p + (size_t)A);
    float4 z2 = ldnt4(p + 2 * (size_t)A);
    float4 z3 = ldnt4(p + 3 * (size_t)A);
    float4 z4 = ldnt4(p + 4 * (size_t)A);

    // ---- wave 0 reg loads (consumed in the match phase, after the barrier) ----
    const int am = a0 + lane;
    const bool amv = am < A;
    float rx = 0.f, ry = 0.f, rw = 0.f, rh = 0.f;
    {
        const float* rp = regp + (size_t)(b * 4) * (size_t)A + (amv ? am : 0);
        if (wave == 0) { rx = ldnt(rp); ry = ldnt(rp + A); rw = ldnt(rp + 2 * (size_t)A); rh = ldnt(rp + 3 * (size_t)A); }
    }

    // ---- stage targets + per-image compaction (single barrier) ----
    // s_list uses fixed per-wave segments -> no cross-wave prefix needed.
    {
        float4 t4 = reinterpret_cast<const float4*>(tboxes)[tid];
        s_x1[tid] = t4.x; s_y1[tid] = t4.y; s_x2[tid] = t4.z; s_y2[tid] = t4.w;
        s_ar[tid] = (t4.z - t4.x) * (t4.w - t4.y);
        s_tc[tid] = t_cls[tid];
    }
    int match = (t_batch[tid] == b) ? 1 : 0;
    unsigned long long mask = __ballot(match != 0);
    if (lane == 0) s_wcnt[wave] = __popcll(mask);
    if (match) {
        int pfx = __popcll(mask & (((unsigned long long)1 << lane) - 1ull));
        s_list[wave * 64 + pfx] = tid;   // ascending within segment
    }
    __syncthreads();

    // ---- wave 0: match phase (registers already resident) ----
    float cnt = 0.f, boxs = 0.f;
    if (wave == 0) {
        if (amv) {
            float gx = (float)(am % H), gy = (float)(am / H);
            float x = (1.f / (1.f + expf(-rx)) + gx) * stride;
            float y = (1.f / (1.f + expf(-ry)) + gy) * stride;
            float w = expf(rw) * stride;
            float h = expf(rh) * stride;
            float px1 = x - 0.5f * w, py1 = y - 0.5f * h;
            float px2 = x + 0.5f * w, py2 = y + 0.5f * h;
            float pw = px2 - px1, ph = py2 - py1;
            float parea = pw * ph;

            float maxiou = -1.f; int best = 0;
            // segments in wave order == ascending tid -> first-max tie kept
            #pragma unroll
            for (int w4 = 0; w4 < 4; ++w4) {
                const int cw = s_wcnt[w4];
                for (int j = 0; j < cw; ++j) {
                    int t = s_list[w4 * 64 + j];
                    float ix = fminf(px2, s_x2[t]) - fmaxf(px1, s_x1[t]);
                    float iy = fminf(py2, s_y2[t]) - fmaxf(py1, s_y1[t]);
                    float inter = fmaxf(ix, 0.f) * fmaxf(iy, 0.f);
                    float iou = inter / (parea + s_ar[t] - inter + EPSF);
                    if (iou > maxiou) { maxiou = iou; best = t; }
                }
            }
            const bool pos = maxiou > 0.5f;
            s_btc[lane] = pos ? s_tc[best] : -1;

            if (pos) {
                cnt = 1.f;
                float gx1 = s_x1[best], gy1 = s_y1[best], gx2 = s_x2[best], gy2 = s_y2[best];
                float gw = gx2 - gx1, gh = gy2 - gy1;
                float ix = fminf(px2, gx2) - fmaxf(px1, gx1);
                float iy = fminf(py2, gy2) - fmaxf(py1, gy1);
                float inter = fmaxf(ix, 0.f) * fmaxf(iy, 0.f);
                float uni = parea + gw * gh - inter + EPSF;
                float iou = inter / uni;
                float cw = fmaxf(px2, gx2) - fminf(px1, gx1);
                float ch = fmaxf(py2, gy2) - fminf(py1, gy1);
                float c2 = cw * cw + ch * ch + EPSF;
                float dx = 0.5f * ((px1 + px2) - (gx1 + gx2));
                float dy = 0.5f * ((py1 + py2) - (gy1 + gy2));
                float rho2 = dx * dx + dy * dy;
                float dv = atanf(gw / (gh + EPSF)) - atanf(pw / (ph + EPSF));
                float v = 0.40528473456935108577f * dv * dv;   // (4/pi^2) dv^2
                float alpha = v / (v - iou + 1.f + EPSF);
                boxs = 1.f - (iou - rho2 / c2 - alpha * v);
            }
        } else {
            s_btc[lane] = -1;
        }
    }

    // ---- class max: 5-way in-register, publish per-(wave,cq,ag) via LDS ----
    // flat index [wave][cq][ag] == wave*64+cq*16+ag == tid -> conflict-free b128.
    {
        float4 mx;
        mx.x = fmaxf(fmaxf(fmaxf(z0.x, z1.x), fmaxf(z2.x, z3.x)), z4.x);
        mx.y = fmaxf(fmaxf(fmaxf(z0.y, z1.y), fmaxf(z2.y, z3.y)), z4.y);
        mx.z = fmaxf(fmaxf(fmaxf(z0.z, z1.z), fmaxf(z2.z, z3.z)), z4.z);
        mx.w = fmaxf(fmaxf(fmaxf(z0.w, z1.w), fmaxf(z2.w, z3.w)), z4.w);
        s_wmax4[tid] = mx;
    }
    __syncthreads();   // publishes s_wmax4 and wave 0's s_btc

    // ---- cls-BCE on live registers (pos anchors only) ----
    float clss = 0.f;
    bool lanepos;
    {
        int4 t4 = *reinterpret_cast<const int4*>(&s_btc[4 * ag]);
        lanepos = (t4.x >= 0) | (t4.y >= 0) | (t4.z >= 0) | (t4.w >= 0);
        if (lanepos) {
            const float4 zz[5] = { z0, z1, z2, z3, z4 };
            #pragma unroll
            for (int k = 0; k < 5; ++k) {
                const int cg = cbase + k;
                if (t4.x >= 0) { clss += softplusf(zz[k].x); if (cg == t4.x) clss -= zz[k].x; }
                if (t4.y >= 0) { clss += softplusf(zz[k].y); if (cg == t4.y) clss -= zz[k].y; }
                if (t4.z >= 0) { clss += softplusf(zz[k].z); if (cg == t4.z) clss -= zz[k].z; }
                if (t4.w >= 0) { clss += softplusf(zz[k].w); if (cg == t4.w) clss -= zz[k].w; }
            }
        }
    }

    // ---- obj (wave 0, one slot per lane): max over 16 (wave,cq) strips ----
    // read pattern wm[(w*4+q)*64 + lane]: 64 consecutive floats -> conflict-free.
    float objs = 0.f;
    if (wave == 0 && amv) {
        const float* wm = reinterpret_cast<const float*>(s_wmax4);
        float m = -INFINITY;
        #pragma unroll
        for (int wq = 0; wq < 16; ++wq)
            m = fmaxf(m, wm[wq * 64 + lane]);
        bool pos = s_btc[lane] >= 0;
        objs = softplusf(m) - (pos ? m : 0.f);
    }

    // ---- reductions: clss ballot-gated (all waves); cnt/box/obj wave-0 only ----
    unsigned long long bp = __ballot(lanepos);
    if (bp) {
        #pragma unroll
        for (int off = 32; off > 0; off >>= 1)
            clss += __shfl_down(clss, off, 64);
    }
    if (lane == 0) s_red[wave][2] = clss;
    if (wave == 0) {
        #pragma unroll
        for (int off = 32; off > 0; off >>= 1) {
            cnt  += __shfl_down(cnt,  off, 64);
            boxs += __shfl_down(boxs, off, 64);
            objs += __shfl_down(objs, off, 64);
        }
        if (lane == 0) { s_red[0][0] = cnt; s_red[0][1] = boxs; s_red[0][3] = objs; }
    }
    __syncthreads();
    if (tid == 0) {
        float4 v;
        v.x = s_red[0][0];
        v.y = s_red[0][1];
        v.z = s_red[0][2] + s_red[1][2] + s_red[2][2] + s_red[3][2];
        v.w = s_red[0][3];
        pblk[bid] = v;
    }
}

// ---- K2: fold the 2112 partials (34KB, L2/L3-hot). Launch boundary = sync. ----
__global__ __launch_bounds__(256)
void yolo_finalize(const float4* __restrict__ pblk, float* __restrict__ out)
{
    __shared__ float s_red[4][12];
    const int tid = threadIdx.x, lane = tid & 63, wave = tid >> 6;

    float v[12];
    #pragma unroll
    for (int j = 0; j < 12; ++j) v[j] = 0.f;
    for (int i = tid; i < NBLK; i += 256) {
        float4 q = pblk[i];
        int k = (i < 1600) ? 0 : (i < 2000) ? 4 : 8;
        v[k + 0] += q.x; v[k + 1] += q.y; v[k + 2] += q.z; v[k + 3] += q.w;
    }
    #pragma unroll
    for (int off = 32; off > 0; off >>= 1) {
        #pragma unroll
        for (int j = 0; j < 12; ++j) v[j] += __shfl_down(v[j], off, 64);
    }
    if (lane == 0) {
        #pragma unroll
        for (int j = 0; j < 12; ++j) s_red[wave][j] = v[j];
    }
    __syncthreads();
    if (tid == 0) {
        float t[12];
        #pragma unroll
        for (int j = 0; j < 12; ++j)
            t[j] = s_red[0][j] + s_red[1][j] + s_red[2][j] + s_red[3][j];
        const float inv_anch[3] = { 1.f / (16.f * 6400.f), 1.f / (16.f * 1600.f), 1.f / (16.f * 400.f) };
        float total = 0.f;
        #pragma unroll
        for (int k = 0; k < 3; ++k) {
            float np = fmaxf(t[k * 4 + 0], 1.f);
            total += 7.5f * t[k * 4 + 1] / np
                   + 0.5f * t[k * 4 + 2] / (np * (float)C_NUM)
                   + t[k * 4 + 3] * inv_anch[k];
        }
        out[0] = total;
    }
}

extern "C" void kernel_launch(void* const* d_in, const int* in_sizes, int n_in,
                              void* d_out, int out_size, void* d_ws, size_t ws_size,
                              hipStream_t stream) {
    const float *cls[3] = {nullptr, nullptr, nullptr};
    const float *reg[3] = {nullptr, nullptr, nullptr};
    const float *tboxes = nullptr;
    const int *t_batch = nullptr, *t_cls = nullptr;
    for (int i = 0; i < n_in; ++i) {
        switch (in_sizes[i]) {
            case 16 * 80 * 6400: cls[0] = (const float*)d_in[i]; break;
            case 16 * 80 * 1600: cls[1] = (const float*)d_in[i]; break;
            case 16 * 80 * 400:  cls[2] = (const float*)d_in[i]; break;
            case 16 * 4 * 6400:  reg[0] = (const float*)d_in[i]; break;
            case 16 * 4 * 1600:  reg[1] = (const float*)d_in[i]; break;
            case 16 * 4 * 400:   reg[2] = (const float*)d_in[i]; break;
            case 256 * 4:        tboxes = (const float*)d_in[i]; break;
            case 256:
                if (!t_batch) t_batch = (const int*)d_in[i];
                else          t_cls   = (const int*)d_in[i];
                break;
            default: break;
        }
    }
    float4* pblk = (float4*)d_ws;       // 2112 float4 partials, all written each call
    float*  out  = (float*)d_out;

    hipLaunchKernelGGL(yolo_main, dim3(NBLK), dim3(256), 0, stream,
                       cls[0], cls[1], cls[2], reg[0], reg[1], reg[2],
                       tboxes, t_batch, t_cls, pblk);
    hipLaunchKernelGGL(yolo_finalize, dim3(1), dim3(256), 0, stream, pblk, out);
}

// Round 5
// 105.261 us; speedup vs baseline: 1.0625x; 1.0625x over previous
//
#include <hip/hip_runtime.h>
#include <math.h>

#define C_NUM 80
#define T_NUM 256
#define EPSF  1e-7f
#define NBLK  1072              // 800 (s0,50/img) + 208 (s1,13/img) + 64 (s2,4/img)

__device__ __forceinline__ float softplusf(float z) {
    return fmaxf(z, 0.0f) + log1pf(expf(-fabsf(z)));
}

// One block = 128 anchor slots of ONE (scale, image). 1072 blocks.
// Wave w owns classes [20w,20w+20); lane=(cq,ag): cq=lane>>4 -> 5-class strip,
// ag=lane&15 -> float4 anchor group; each thread covers TWO groups (halves
// h=0/1 at a0+4ag and a0+64+4ag -> 10 dwordx4 loads, 2x the MLP of R8).
// Waves 0 AND 1 run the match phase (64 anchors each) in parallel.
//
// R11 vs R10: NT loads REVERTED (R10 measured -5us: nt MTYPE degrades the
// read path; the stream is compulsory-miss so NT had nothing to save).
// Blocks fattened 64->128 anchors: halves per-block staging (6KB targets
// re-read 2112x -> 1072x), halves barrier/launch count, parallelizes match
// across 2 waves instead of serial-on-wave-0.
//
// NO fences / NO completion counter: per-block partials are plain stores;
// a second kernel (launch boundary = the sync) folds them. R5-R7 showed
// __threadfence's per-block L2 writeback serializes at ~35-70ns/block.
// Workspace re-poisoning forbids atomic-counter last-block folding.
__global__ __launch_bounds__(256)
void yolo_main(const float* __restrict__ cls0, const float* __restrict__ cls1,
               const float* __restrict__ cls2,
               const float* __restrict__ reg0, const float* __restrict__ reg1,
               const float* __restrict__ reg2,
               const float* __restrict__ tboxes, const int* __restrict__ t_batch,
               const int* __restrict__ t_cls, float4* __restrict__ pblk)
{
    __shared__ float s_x1[T_NUM], s_y1[T_NUM], s_x2[T_NUM], s_y2[T_NUM], s_ar[T_NUM];
    __shared__ int   s_tc[T_NUM];
    __shared__ int   s_list[T_NUM];   // 4 segments of 64: wave w owns [64w, 64w+cnt_w)
    __shared__ int   s_wcnt[4];
    __shared__ float4 s_wmax4[2][256]; // [half][wave*64+cq*16+ag]: 5-class max of 4 anchors
    __shared__ int   s_btc[128] __attribute__((aligned(16)));
    __shared__ float s_red[4][4];

    const int tid = threadIdx.x;
    const int bid = blockIdx.x;
    const int lane = tid & 63, wave = tid >> 6;
    const int cq = lane >> 4, ag = lane & 15;

    int b, a0, A, H; float stride;
    const float *clsp, *regp;
    if (bid < 800)       { b = bid / 50;            a0 = (bid % 50) * 128; A = 6400; H = 80; stride =  8.f; clsp = cls0; regp = reg0; }
    else if (bid < 1008) { int r = bid - 800;  b = r / 13; a0 = (r % 13) * 128; A = 1600; H = 40; stride = 16.f; clsp = cls1; regp = reg1; }
    else                 { int r = bid - 1008; b = r / 4;  a0 = (r % 4)  * 128; A = 400;  H = 20; stride = 32.f; clsp = cls2; regp = reg2; }

    // ---- staging loads FIRST (small; retire before the class stream) ----
    float4 t4 = reinterpret_cast<const float4*>(tboxes)[tid];
    int    tb = t_batch[tid];
    int    tc = t_cls[tid];

    // ---- reg loads (waves 0,1 = match waves; consumed after barrier) ----
    const int am = a0 + (wave << 6) + lane;       // anchor for match waves
    const bool amv = (wave < 2) && (am < A);
    float rx = 0.f, ry = 0.f, rw = 0.f, rh = 0.f;
    if (wave < 2) {
        const float* rp = regp + (size_t)(b * 4) * (size_t)A + (amv ? am : a0);
        rx = rp[0]; ry = rp[A]; rw = rp[2 * (size_t)A]; rh = rp[3 * (size_t)A];
    }

    // ---- the 43MB class stream: 10 independent dwordx4 per thread ----
    const int cbase = wave * 20 + cq * 5;
    const int ga0 = a0 + 4 * ag;
    const int ga1 = a0 + 64 + 4 * ag;
    const float* pc = clsp + ((size_t)(b * C_NUM + cbase)) * (size_t)A;
    const float* p0 = pc + ((ga0 < A) ? ga0 : a0);
    const float* p1 = pc + ((ga1 < A) ? ga1 : a0);
    float4 za0 = *reinterpret_cast<const float4*>(p0);
    float4 za1 = *reinterpret_cast<const float4*>(p0 + (size_t)A);
    float4 za2 = *reinterpret_cast<const float4*>(p0 + 2 * (size_t)A);
    float4 za3 = *reinterpret_cast<const float4*>(p0 + 3 * (size_t)A);
    float4 za4 = *reinterpret_cast<const float4*>(p0 + 4 * (size_t)A);
    float4 zb0 = *reinterpret_cast<const float4*>(p1);
    float4 zb1 = *reinterpret_cast<const float4*>(p1 + (size_t)A);
    float4 zb2 = *reinterpret_cast<const float4*>(p1 + 2 * (size_t)A);
    float4 zb3 = *reinterpret_cast<const float4*>(p1 + 3 * (size_t)A);
    float4 zb4 = *reinterpret_cast<const float4*>(p1 + 4 * (size_t)A);

    // ---- stage targets + per-image compaction (single barrier) ----
    s_x1[tid] = t4.x; s_y1[tid] = t4.y; s_x2[tid] = t4.z; s_y2[tid] = t4.w;
    s_ar[tid] = (t4.z - t4.x) * (t4.w - t4.y);
    s_tc[tid] = tc;
    int match = (tb == b) ? 1 : 0;
    unsigned long long mask = __ballot(match != 0);
    if (lane == 0) s_wcnt[wave] = __popcll(mask);
    if (match) {
        int pfx = __popcll(mask & (((unsigned long long)1 << lane) - 1ull));
        s_list[wave * 64 + pfx] = tid;   // ascending within segment
    }
    __syncthreads();

    // ---- waves 0,1: match phase, 64 anchors each, in parallel ----
    float cnt = 0.f, boxs = 0.f;
    if (wave < 2) {
        const int slot = (wave << 6) + lane;
        if (amv) {
            float gx = (float)(am % H), gy = (float)(am / H);
            float x = (1.f / (1.f + expf(-rx)) + gx) * stride;
            float y = (1.f / (1.f + expf(-ry)) + gy) * stride;
            float w = expf(rw) * stride;
            float h = expf(rh) * stride;
            float px1 = x - 0.5f * w, py1 = y - 0.5f * h;
            float px2 = x + 0.5f * w, py2 = y + 0.5f * h;
            float pw = px2 - px1, ph = py2 - py1;
            float parea = pw * ph;

            float maxiou = -1.f; int best = 0;
            // segments in wave order == ascending tid -> first-max tie kept
            #pragma unroll
            for (int w4 = 0; w4 < 4; ++w4) {
                const int cw = s_wcnt[w4];
                for (int j = 0; j < cw; ++j) {
                    int t = s_list[w4 * 64 + j];
                    float ix = fminf(px2, s_x2[t]) - fmaxf(px1, s_x1[t]);
                    float iy = fminf(py2, s_y2[t]) - fmaxf(py1, s_y1[t]);
                    float inter = fmaxf(ix, 0.f) * fmaxf(iy, 0.f);
                    float iou = inter / (parea + s_ar[t] - inter + EPSF);
                    if (iou > maxiou) { maxiou = iou; best = t; }
                }
            }
            const bool pos = maxiou > 0.5f;
            s_btc[slot] = pos ? s_tc[best] : -1;

            if (pos) {
                cnt = 1.f;
                float gx1 = s_x1[best], gy1 = s_y1[best], gx2 = s_x2[best], gy2 = s_y2[best];
                float gw = gx2 - gx1, gh = gy2 - gy1;
                float ix = fminf(px2, gx2) - fmaxf(px1, gx1);
                float iy = fminf(py2, gy2) - fmaxf(py1, gy1);
                float inter = fmaxf(ix, 0.f) * fmaxf(iy, 0.f);
                float uni = parea + gw * gh - inter + EPSF;
                float iou = inter / uni;
                float cw = fmaxf(px2, gx2) - fminf(px1, gx1);
                float ch = fmaxf(py2, gy2) - fminf(py1, gy1);
                float c2 = cw * cw + ch * ch + EPSF;
                float dx = 0.5f * ((px1 + px2) - (gx1 + gx2));
                float dy = 0.5f * ((py1 + py2) - (gy1 + gy2));
                float rho2 = dx * dx + dy * dy;
                float dv = atanf(gw / (gh + EPSF)) - atanf(pw / (ph + EPSF));
                float v = 0.40528473456935108577f * dv * dv;   // (4/pi^2) dv^2
                float alpha = v / (v - iou + 1.f + EPSF);
                boxs = 1.f - (iou - rho2 / c2 - alpha * v);
            }
        } else {
            s_btc[slot] = -1;
        }
    }

    // ---- class max per half: 5-way in-register, publish via LDS ----
    // flat [wave][cq][ag] == tid within each half -> conflict-free b128.
    {
        float4 mx;
        mx.x = fmaxf(fmaxf(fmaxf(za0.x, za1.x), fmaxf(za2.x, za3.x)), za4.x);
        mx.y = fmaxf(fmaxf(fmaxf(za0.y, za1.y), fmaxf(za2.y, za3.y)), za4.y);
        mx.z = fmaxf(fmaxf(fmaxf(za0.z, za1.z), fmaxf(za2.z, za3.z)), za4.z);
        mx.w = fmaxf(fmaxf(fmaxf(za0.w, za1.w), fmaxf(za2.w, za3.w)), za4.w);
        s_wmax4[0][tid] = mx;
        mx.x = fmaxf(fmaxf(fmaxf(zb0.x, zb1.x), fmaxf(zb2.x, zb3.x)), zb4.x);
        mx.y = fmaxf(fmaxf(fmaxf(zb0.y, zb1.y), fmaxf(zb2.y, zb3.y)), zb4.y);
        mx.z = fmaxf(fmaxf(fmaxf(zb0.z, zb1.z), fmaxf(zb2.z, zb3.z)), zb4.z);
        mx.w = fmaxf(fmaxf(fmaxf(zb0.w, zb1.w), fmaxf(zb2.w, zb3.w)), zb4.w);
        s_wmax4[1][tid] = mx;
    }
    __syncthreads();   // publishes s_wmax4 and the match waves' s_btc

    // ---- cls-BCE on live registers (pos anchors only), both halves ----
    float clss = 0.f;
    bool lanepos;
    {
        int4 ta = *reinterpret_cast<const int4*>(&s_btc[4 * ag]);        // half 0
        int4 tb4 = *reinterpret_cast<const int4*>(&s_btc[64 + 4 * ag]);  // half 1
        bool pa = (ta.x >= 0) | (ta.y >= 0) | (ta.z >= 0) | (ta.w >= 0);
        bool pb = (tb4.x >= 0) | (tb4.y >= 0) | (tb4.z >= 0) | (tb4.w >= 0);
        lanepos = pa | pb;
        if (pa) {
            const float4 zz[5] = { za0, za1, za2, za3, za4 };
            #pragma unroll
            for (int k = 0; k < 5; ++k) {
                const int cg = cbase + k;
                if (ta.x >= 0) { clss += softplusf(zz[k].x); if (cg == ta.x) clss -= zz[k].x; }
                if (ta.y >= 0) { clss += softplusf(zz[k].y); if (cg == ta.y) clss -= zz[k].y; }
                if (ta.z >= 0) { clss += softplusf(zz[k].z); if (cg == ta.z) clss -= zz[k].z; }
                if (ta.w >= 0) { clss += softplusf(zz[k].w); if (cg == ta.w) clss -= zz[k].w; }
            }
        }
        if (pb) {
            const float4 zz[5] = { zb0, zb1, zb2, zb3, zb4 };
            #pragma unroll
            for (int k = 0; k < 5; ++k) {
                const int cg = cbase + k;
                if (tb4.x >= 0) { clss += softplusf(zz[k].x); if (cg == tb4.x) clss -= zz[k].x; }
                if (tb4.y >= 0) { clss += softplusf(zz[k].y); if (cg == tb4.y) clss -= zz[k].y; }
                if (tb4.z >= 0) { clss += softplusf(zz[k].z); if (cg == tb4.z) clss -= zz[k].z; }
                if (tb4.w >= 0) { clss += softplusf(zz[k].w); if (cg == tb4.w) clss -= zz[k].w; }
            }
        }
    }

    // ---- obj (waves 0,1; one anchor per lane): max over 16 (w,cq) strips ----
    // read wm[wq*64 + lane]: 64 consecutive floats -> conflict-free.
    float objs = 0.f;
    if (wave < 2 && amv) {
        const float* wm = reinterpret_cast<const float*>(s_wmax4[wave]);
        float m = -INFINITY;
        #pragma unroll
        for (int wq = 0; wq < 16; ++wq)
            m = fmaxf(m, wm[wq * 64 + lane]);
        bool pos = s_btc[(wave << 6) + lane] >= 0;
        objs = softplusf(m) - (pos ? m : 0.f);
    }

    // ---- reductions: clss ballot-gated (all waves); cnt/box/obj waves 0,1 ----
    unsigned long long bp = __ballot(lanepos);
    if (bp) {
        #pragma unroll
        for (int off = 32; off > 0; off >>= 1)
            clss += __shfl_down(clss, off, 64);
    }
    if (lane == 0) s_red[wave][2] = clss;
    if (wave < 2) {
        #pragma unroll
        for (int off = 32; off > 0; off >>= 1) {
            cnt  += __shfl_down(cnt,  off, 64);
            boxs += __shfl_down(boxs, off, 64);
            objs += __shfl_down(objs, off, 64);
        }
        if (lane == 0) { s_red[wave][0] = cnt; s_red[wave][1] = boxs; s_red[wave][3] = objs; }
    }
    __syncthreads();
    if (tid == 0) {
        float4 v;
        v.x = s_red[0][0] + s_red[1][0];
        v.y = s_red[0][1] + s_red[1][1];
        v.z = s_red[0][2] + s_red[1][2] + s_red[2][2] + s_red[3][2];
        v.w = s_red[0][3] + s_red[1][3];
        pblk[bid] = v;
    }
}

// ---- K2: fold the 1072 partials (17KB, L2-hot). Launch boundary = sync. ----
__global__ __launch_bounds__(256)
void yolo_finalize(const float4* __restrict__ pblk, float* __restrict__ out)
{
    __shared__ float s_red[4][12];
    const int tid = threadIdx.x, lane = tid & 63, wave = tid >> 6;

    float v[12];
    #pragma unroll
    for (int j = 0; j < 12; ++j) v[j] = 0.f;
    for (int i = tid; i < NBLK; i += 256) {
        float4 q = pblk[i];
        int k = (i < 800) ? 0 : (i < 1008) ? 4 : 8;
        v[k + 0] += q.x; v[k + 1] += q.y; v[k + 2] += q.z; v[k + 3] += q.w;
    }
    #pragma unroll
    for (int off = 32; off > 0; off >>= 1) {
        #pragma unroll
        for (int j = 0; j < 12; ++j) v[j] += __shfl_down(v[j], off, 64);
    }
    if (lane == 0) {
        #pragma unroll
        for (int j = 0; j < 12; ++j) s_red[wave][j] = v[j];
    }
    __syncthreads();
    if (tid == 0) {
        float t[12];
        #pragma unroll
        for (int j = 0; j < 12; ++j)
            t[j] = s_red[0][j] + s_red[1][j] + s_red[2][j] + s_red[3][j];
        const float inv_anch[3] = { 1.f / (16.f * 6400.f), 1.f / (16.f * 1600.f), 1.f / (16.f * 400.f) };
        float total = 0.f;
        #pragma unroll
        for (int k = 0; k < 3; ++k) {
            float np = fmaxf(t[k * 4 + 0], 1.f);
            total += 7.5f * t[k * 4 + 1] / np
                   + 0.5f * t[k * 4 + 2] / (np * (float)C_NUM)
                   + t[k * 4 + 3] * inv_anch[k];
        }
        out[0] = total;
    }
}

extern "C" void kernel_launch(void* const* d_in, const int* in_sizes, int n_in,
                              void* d_out, int out_size, void* d_ws, size_t ws_size,
                              hipStream_t stream) {
    const float *cls[3] = {nullptr, nullptr, nullptr};
    const float *reg[3] = {nullptr, nullptr, nullptr};
    const float *tboxes = nullptr;
    const int *t_batch = nullptr, *t_cls = nullptr;
    for (int i = 0; i < n_in; ++i) {
        switch (in_sizes[i]) {
            case 16 * 80 * 6400: cls[0] = (const float*)d_in[i]; break;
            case 16 * 80 * 1600: cls[1] = (const float*)d_in[i]; break;
            case 16 * 80 * 400:  cls[2] = (const float*)d_in[i]; break;
            case 16 * 4 * 6400:  reg[0] = (const float*)d_in[i]; break;
            case 16 * 4 * 1600:  reg[1] = (const float*)d_in[i]; break;
            case 16 * 4 * 400:   reg[2] = (const float*)d_in[i]; break;
            case 256 * 4:        tboxes = (const float*)d_in[i]; break;
            case 256:
                if (!t_batch) t_batch = (const int*)d_in[i];
                else          t_cls   = (const int*)d_in[i];
                break;
            default: break;
        }
    }
    float4* pblk = (float4*)d_ws;       // 1072 float4 partials, all written each call
    float*  out  = (float*)d_out;

    hipLaunchKernelGGL(yolo_main, dim3(NBLK), dim3(256), 0, stream,
                       cls[0], cls[1], cls[2], reg[0], reg[1], reg[2],
                       tboxes, t_batch, t_cls, pblk);
    hipLaunchKernelGGL(yolo_finalize, dim3(1), dim3(256), 0, stream, pblk, out);
}